// Round 22
// baseline (133.724 us; speedup 1.0000x reference)
//
#include <hip/hip_runtime.h>
#include <hip/hip_fp16.h>
#include <math.h>

#define PI_F      3.14159265358979323846f
#define TWO_PI_F  6.28318530717958647692f
#define PI4_F     0.78539816339744830962f   // pi/4 == ROT_SCALE == 2pi/8

typedef _Float16 f16x8 __attribute__((ext_vector_type(8)));
typedef float    f32x4 __attribute__((ext_vector_type(4)));

#define GUARD_OFF  ((size_t)104 * 1024)               // 4 KB zeros
#define XHP_OFF    ((size_t)1 << 17)                  // 128 KB
#define XHP_ROW    (260 * 64)                         // 16,640 B per padded row
#define XHP_BATCH  ((size_t)256 * XHP_ROW)            // 4,259,840 B
#define XHP_BYTES  ((size_t)8 * XHP_BATCH)            // 34,078,720 B

__device__ __forceinline__ float sgn(float t) {
    return (t > 0.f) ? 1.f : ((t < 0.f) ? -1.f : 0.f);
}

__device__ __forceinline__ float b2(float x) {
    float a = x - 0.5f;
    float b = x - 1.5f;
    float c = 1.f + 2.f * x;
    float d = 3.f + 2.f * x;
    return (-3.f * a * a * sgn(0.5f - x)
            + b * b * sgn(1.5f - x)
            - 0.75f * c * c * sgn(0.5f + x)
            + 0.25f * d * d * sgn(1.5f + x)) * 0.25f;
}

// ks_h[t][O][I] fp16.  t = dx*5+dy, O = r0*8+o, I = i*8+r.  Also zeroes guard.
__global__ void build_ks_kernel(const float* __restrict__ w, __half* __restrict__ ksh,
                                float* __restrict__ guard) {
    if (blockIdx.x < 4) guard[blockIdx.x * 256 + threadIdx.x] = 0.f;   // 4 KB zeros
    int g = blockIdx.x * 256 + threadIdx.x;
    if (g >= 64 * 32 * 25) return;
    int O = g & 63;
    int rest = g >> 6;
    int t = rest % 25;
    int I = rest / 25;
    int r0 = O >> 3, o = O & 7;
    int i = I >> 3, r = I & 7;
    int x = t / 5, y = t % 5;

    float theta = -(float)r0 * PI4_F;
    float cth = cosf(theta), sth = sinf(theta);
    float fx = (float)(x - 2), fy = (float)(y - 2);
    float xc = fx * cth - fy * sth;
    float yc = fx * sth + fy * cth;

    float rotv[8];
    float rs = (float)r * PI4_F + theta;
    #pragma unroll
    for (int mr = 0; mr < 8; ++mr) {
        float v = (float)mr * PI4_F - rs + PI_F;
        float md = fmodf(v, TWO_PI_F);
        if (md < 0.f) md += TWO_PI_F;
        rotv[mr] = b2((md - PI_F) / PI4_F);
    }

    float sum = 0.f;
    for (int mx = 0; mx < 25; ++mx) {
        float cx = (float)(mx / 5 - 2);
        float cy = (float)(mx % 5 - 2);
        float bx = b2(cx - xc) * b2(cy - yc);
        if (bx != 0.f) {
            const float* wp = w + (size_t)(i * 200 + mx * 8) * 8 + o;
            #pragma unroll
            for (int mr = 0; mr < 8; ++mr)
                sum = fmaf(bx * rotv[mr], wp[mr * 8], sum);
        }
    }
    ksh[(size_t)(t * 64 + O) * 32 + I] = __float2half(sum);
}

// X (b,32ch,256,256) f32 -> XhP (b,256,260,32ch) fp16, w-padded by 2 each side
// (zeros). One block per (b,h). Threads 0-3 also zero the 4 pad pixels.
__global__ __launch_bounds__(256, 4) void hwcpad_kernel(const float* __restrict__ X,
                                                        char* __restrict__ XhP) {
    int b = blockIdx.x >> 8;
    int h = blockIdx.x & 255;
    int ww = threadIdx.x;
    const float* Xb = X + ((size_t)b * 32) * 65536 + h * 256 + ww;
    char* rowp = XhP + (size_t)b * XHP_BATCH + (size_t)h * XHP_ROW;

    union { __half hh[8]; uint4 u; } pk[4];
    #pragma unroll
    for (int c = 0; c < 32; ++c)
        pk[c >> 3].hh[c & 7] = __float2half(Xb[(size_t)c * 65536]);

    uint4* dst = (uint4*)(rowp + (ww + 2) * 64);
    #pragma unroll
    for (int kk = 0; kk < 4; ++kk) dst[kk] = pk[kk].u;

    if (ww < 4) {
        int pos = (ww < 2) ? ww : (256 + ww);      // 0,1,258,259
        uint4* pz = (uint4*)(rowp + pos * 64);
        uint4 z = make_uint4(0u, 0u, 0u, 0u);
        pz[0] = z; pz[1] = z; pz[2] = z; pz[3] = z;
    }
}

// Phase-free wave-streaming implicit-GEMM conv: NO LDS, NO barriers.
// 2048 blocks x 256 thr; each WAVE independently owns a 2h x 32w x 64O tile.
// A-fragments (16 px x 8 ch = 16 B/lane) load straight from padded fp16 HWC
// global (L1/L2-served; same 6x36-px window re-read across all 25 taps).
// h-boundary via wave-uniform guard-pointer select (4 KB zeros); w handled
// by padding. 1-tap-deep A+B register prefetch; 16 MFMA/tap; async stores.
// FIX vs r21: padded column index = gw + 2 and gw = w0 + col + dy - 2, so
// the base is w0*64 (the previous (w0+2)*64 double-counted the pad: +2 col
// shift, absmax 78).
__global__ __launch_bounds__(256, 3) void conv_direct_kernel(const char* __restrict__ XhP,
                                                             const __half* __restrict__ ksh,
                                                             const char* __restrict__ guard,
                                                             float* __restrict__ out) {
    int tid = threadIdx.x;
    int wave = tid >> 6, lane = tid & 63;
    int wid = blockIdx.x * 4 + wave;
    int b   = wid >> 10;                 // 8 batches, b-major
    int rem = wid & 1023;                // 128 row-pairs x 8 w-strips
    int h0  = (rem >> 3) << 1;           // 0..254 step 2
    int w0  = (rem & 7) << 5;            // 0..224 step 32

    int lO = lane & 15, ks4 = lane >> 4;
    int lanebyte = lO * 64 + ks4 * 16;
    int bidx = lO * 4 + ks4;
    const uint4* ksq = (const uint4*)ksh;

    const char* Xb = XhP + (size_t)b * XHP_BATCH + (size_t)w0 * 64;   // FIXED: no +2

    // row pointers for dx = 0..4, rr = 0..1 (wave-uniform validity select)
    const char* rowp[5][2];
    #pragma unroll
    for (int dx = 0; dx < 5; ++dx) {
        #pragma unroll
        for (int rr = 0; rr < 2; ++rr) {
            int gh = h0 + rr + dx - 2;
            rowp[dx][rr] = ((unsigned)gh < 256u)
                ? Xb + (size_t)gh * XHP_ROW + lanebyte
                : guard + lanebyte;
        }
    }

    f32x4 acc[4][4] = {};
    f16x8 Af[2][4], Bf[2][4];

    // prologue: tap 0 fragments
    #pragma unroll
    for (int m = 0; m < 4; ++m)
        Af[0][m] = __builtin_bit_cast(f16x8,
            *(const uint4*)(rowp[0][m >> 1] + (m & 1) * 1024));
    #pragma unroll
    for (int n = 0; n < 4; ++n)
        Bf[0][n] = __builtin_bit_cast(f16x8, ksq[n * 64 + bidx]);

    #pragma unroll
    for (int t = 0; t < 25; ++t) {
        const int cur = t & 1, nxt = cur ^ 1;

        if (t < 24) {
            const int t1 = t + 1;
            const int dx1 = t1 / 5, dy1 = t1 % 5;
            #pragma unroll
            for (int m = 0; m < 4; ++m)
                Af[nxt][m] = __builtin_bit_cast(f16x8,
                    *(const uint4*)(rowp[dx1][m >> 1] + (m & 1) * 1024 + dy1 * 64));
            #pragma unroll
            for (int n = 0; n < 4; ++n)
                Bf[nxt][n] = __builtin_bit_cast(f16x8, ksq[t1 * 256 + n * 64 + bidx]);
        }

        #pragma unroll
        for (int m = 0; m < 4; ++m) {
            #pragma unroll
            for (int n = 0; n < 4; ++n)
                acc[m][n] = __builtin_amdgcn_mfma_f32_16x16x32_f16(Af[cur][m], Bf[cur][n], acc[m][n], 0, 0, 0);
        }
    }

    // ---- store: out[b][O&7][O>>3][h][w] * (2pi/8); full 128-B lines ----
    #pragma unroll
    for (int m = 0; m < 4; ++m) {
        int gh  = h0 + (m >> 1);
        int gwb = w0 + (m & 1) * 16 + ks4 * 4;
        #pragma unroll
        for (int n = 0; n < 4; ++n) {
            int O = n * 16 + lO;
            float* op = out + (((size_t)(b * 8 + (O & 7)) * 8 + (O >> 3)) << 16)
                            + gh * 256 + gwb;
            *(f32x4*)op = acc[m][n] * PI4_F;
        }
    }
}

// ---- fallback (small ws): round-20 fused single-pass conv ----
__global__ __launch_bounds__(256, 3) void conv_fused_kernel(const float* __restrict__ X,
                                                            const __half* __restrict__ ksh,
                                                            float* __restrict__ out) {
    __shared__ uint4 xt[4 * 433];
    int bid = blockIdx.x;
    int b   = bid >> 8;
    int rem = bid & 255;
    int h0  = (rem >> 3) << 3;
    int w0  = (rem & 7) << 5;
    int tid = threadIdx.x;
    const float* Xb = X + (size_t)b * 32 * 65536;
    for (int lin = tid; lin < 1728; lin += 256) {
        int slot = lin / 432;
        int p    = lin - slot * 432;
        int r = p / 36, c = p - (p / 36) * 36;
        int gh = h0 + r - 2;
        int gw = w0 + c - 2;
        union { __half hh[8]; uint4 u; } q;
        if ((unsigned)gh < 256u && (unsigned)gw < 256u) {
            const float* src = Xb + (size_t)slot * 8 * 65536 + gh * 256 + gw;
            #pragma unroll
            for (int j = 0; j < 8; ++j) q.hh[j] = __float2half(src[j * 65536]);
        } else {
            q.u = make_uint4(0u, 0u, 0u, 0u);
        }
        xt[slot * 433 + p] = q.u;
    }
    __syncthreads();
    int wave = tid >> 6, lane = tid & 63;
    int lO = lane & 15, ks4 = lane >> 4;
    int bidx = lO * 4 + ks4;
    const uint4* ksq = (const uint4*)ksh;
    f32x4 acc[4][4] = {};
    int baseA[4];
    #pragma unroll
    for (int m = 0; m < 4; ++m)
        baseA[m] = 433 * ks4 + (wave * 2 + (m >> 1)) * 36 + (m & 1) * 16 + lO;
    f16x8 Bf[2][4];
    #pragma unroll
    for (int n = 0; n < 4; ++n)
        Bf[0][n] = __builtin_bit_cast(f16x8, ksq[n * 64 + bidx]);
    #pragma unroll
    for (int t = 0; t < 25; ++t) {
        const int cur = t & 1, nxt = cur ^ 1;
        const int aoff = (t / 5) * 36 + (t % 5);
        f16x8 Af[4];
        #pragma unroll
        for (int m = 0; m < 4; ++m)
            Af[m] = __builtin_bit_cast(f16x8, xt[baseA[m] + aoff]);
        if (t < 24) {
            #pragma unroll
            for (int n = 0; n < 4; ++n)
                Bf[nxt][n] = __builtin_bit_cast(f16x8, ksq[(t + 1) * 256 + n * 64 + bidx]);
        }
        #pragma unroll
        for (int m = 0; m < 4; ++m)
            #pragma unroll
            for (int n = 0; n < 4; ++n)
                acc[m][n] = __builtin_amdgcn_mfma_f32_16x16x32_f16(Af[m], Bf[cur][n], acc[m][n], 0, 0, 0);
    }
    #pragma unroll
    for (int m = 0; m < 4; ++m) {
        int gh  = h0 + wave * 2 + (m >> 1);
        int gwb = w0 + (m & 1) * 16 + ks4 * 4;
        #pragma unroll
        for (int n = 0; n < 4; ++n) {
            int O = n * 16 + lO;
            float* op = out + (((size_t)(b * 8 + (O & 7)) * 8 + (O >> 3)) << 16) + gh * 256 + gwb;
            *(f32x4*)op = acc[m][n] * PI4_F;
        }
    }
}

extern "C" void kernel_launch(void* const* d_in, const int* in_sizes, int n_in,
                              void* d_out, int out_size, void* d_ws, size_t ws_size,
                              hipStream_t stream) {
    const float* X = (const float*)d_in[0];       // (8, 4, 8, 256, 256) f32
    const float* w = (const float*)d_in[1];       // (4, 200, 8) f32
    float* outp = (float*)d_out;                  // (8, 8, 8, 256, 256) f32
    char* ws = (char*)d_ws;
    __half* ksh = (__half*)ws;                    // 102.4 KB
    float* guard = (float*)(ws + GUARD_OFF);      // 4 KB zeros

    build_ks_kernel<<<200, 256, 0, stream>>>(w, ksh, guard);

    if (ws_size >= XHP_OFF + XHP_BYTES) {
        char* XhP = ws + XHP_OFF;                 // 34.08 MB padded fp16 HWC
        hwcpad_kernel<<<8 * 256, 256, 0, stream>>>(X, XhP);
        conv_direct_kernel<<<2048, 256, 0, stream>>>(XhP, ksh, ws + GUARD_OFF, outp);
    } else {
        conv_fused_kernel<<<8 * 256, 256, 0, stream>>>(X, ksh, outp);
    }
}